// Round 3
// baseline (227.522 us; speedup 1.0000x reference)
//
#include <hip/hip_runtime.h>

constexpr float IMG_SIZE = 448.0f;
constexpr float GSZ = 64.0f;           // IMG_SIZE / GRID_NUM
constexpr float LAMBDA_COORD = 5.0f;
constexpr float LAMBDA_NOOBJ = 0.1f;
constexpr float EPSF = 1e-12f;

#define BLOCK 256
#define CPT 2                       // cells per thread
#define TILE (BLOCK * CPT)          // 512 cells per block -> 30 KB LDS, 5 blocks/CU

// Faithful port of reference _iou (including the y1_t = cy_t + w_t/2 typo).
__device__ __forceinline__ float iou_one(const float* __restrict__ b,
                                         float tx, float ty, float tw, float th,
                                         float gj, float gi) {
    float cx_p = b[0] * GSZ + gj * GSZ;
    float cy_p = b[1] * GSZ + gi * GSZ;
    float w_p  = b[2] * IMG_SIZE;
    float h_p  = b[3] * IMG_SIZE;
    float x0p = cx_p - 0.5f * w_p, x1p = cx_p + 0.5f * w_p;
    float y0p = cy_p - 0.5f * h_p, y1p = cy_p + 0.5f * h_p;

    float cx_t = tx * GSZ + gj * GSZ;
    float cy_t = ty * GSZ + gi * GSZ;
    float w_t  = tw * IMG_SIZE;
    float h_t  = th * IMG_SIZE;
    float x0t = cx_t - 0.5f * w_t, x1t = cx_t + 0.5f * w_t;
    float y0t = cy_t - 0.5f * h_t;
    float y1t = cy_t + 0.5f * w_t;   // faithful typo: w_t, not h_t

    float ux0 = fmaxf(x0p, x0t), ux1 = fminf(x1p, x1t);
    float uy0 = fmaxf(y0p, y0t), uy1 = fminf(y1p, y1t);
    bool valid = (ux0 < ux1) && (uy0 < uy1);
    float au = (ux1 - ux0) * (uy1 - uy0);
    float ap = (x1p - x0p) * (y1p - y0p);
    float at = (x1t - x0t) * (y1t - y0t);
    float res = au / (ap + at - au + EPSF);
    return valid ? res : 0.0f;
}

// Per-cell loss contribution (unscaled; reduce kernel applies 1/B).
__device__ __forceinline__ float cell_loss(const float* __restrict__ p,
                                           const float* __restrict__ t,
                                           float gj, float gi) {
    float iou0 = iou_one(p,     t[0], t[1], t[2], t[3], gj, gi);
    float iou1 = iou_one(p + 5, t[0], t[1], t[2], t[3], gj, gi);
    bool obj = (t[4] == 1.0f);
    bool ch0 = iou0 > iou1;
    float loss;
    if (obj) {
        float cp = ch0 ? p[4] : p[9];
        float ct = ch0 ? iou0 : iou1;
        float d  = cp - ct;
        loss = d * d;
        float dx = (ch0 ? p[0] : p[5]) - t[0];
        float dy = (ch0 ? p[1] : p[6]) - t[1];
        loss += LAMBDA_COORD * (dx * dx + dy * dy);
        float wp = fmaxf(ch0 ? p[2] : p[7], EPSF);
        float hp = fmaxf(ch0 ? p[3] : p[8], EPSF);
        float wt = fmaxf(t[2], EPSF);
        float ht = fmaxf(t[3], EPSF);
        float dw = sqrtf(wp) - sqrtf(wt);
        float dh = sqrtf(hp) - sqrtf(ht);
        loss += LAMBDA_COORD * (dw * dw + dh * dh);
    } else {
        loss = LAMBDA_NOOBJ * (p[4] * p[4] + p[9] * p[9]);
    }
    return loss;
}

__global__ __launch_bounds__(BLOCK)
void yolo_loss_kernel(const float* __restrict__ y_pre,
                      const float* __restrict__ y_true,
                      float* __restrict__ partials,
                      int cells) {
    // 512-cell tile: 20 KB pre + 10 KB true = 30 KB LDS -> 5 blocks/CU.
    __shared__ float s_pre[TILE * 10];     // 20 KB
    __shared__ float s_true[TILE * 5];     // 10 KB
    __shared__ float smem[BLOCK / 64];

    int tid = threadIdx.x;
    long long base = (long long)blockIdx.x * TILE;
    int n = cells - (int)base;
    if (n > TILE) n = TILE;

    if (n == TILE) {
        // Full tile: lane i reads float4 i -> 1024 B per wave-instruction.
        const float4* gp = (const float4*)(y_pre + base * 10);
        float4* sp = (float4*)s_pre;
        #pragma unroll
        for (int i = 0; i < TILE * 10 / 4 / BLOCK; ++i)      // 5 iters
            sp[i * BLOCK + tid] = gp[i * BLOCK + tid];
        const float4* gt = (const float4*)(y_true + base * 5);
        float4* st = (float4*)s_true;
        // 640 float4 over 256 threads: 2 full rounds + half round.
        st[tid]         = gt[tid];
        st[BLOCK + tid] = gt[BLOCK + tid];
        if (tid < TILE * 5 / 4 - 2 * BLOCK)                  // 128
            st[2 * BLOCK + tid] = gt[2 * BLOCK + tid];
    } else {
        // Partial tail tile (not hit for B=65536, kept for safety).
        for (int f = tid; f < n * 10; f += BLOCK) s_pre[f] = y_pre[base * 10 + f];
        for (int f = tid; f < n * 5;  f += BLOCK) s_true[f] = y_true[base * 5 + f];
    }
    __syncthreads();

    // Compute: thread handles cells {tid, tid+256} of the tile.
    float local = 0.0f;
    int rc = (int)((base + tid) % 49);     // cell index within the 7x7 image
    #pragma unroll
    for (int j = 0; j < CPT; ++j) {
        int c = tid + j * BLOCK;
        if (c < n) {
            int gi = rc / 7;
            int gj = rc - gi * 7;
            local += cell_loss(&s_pre[c * 10], &s_true[c * 5],
                               (float)gj, (float)gi);
        }
        rc += (BLOCK % 49);                // 256 % 49 == 11
        if (rc >= 49) rc -= 49;
    }

    // Wave-64 shuffle reduce; one plain store per block.
    #pragma unroll
    for (int off = 32; off > 0; off >>= 1)
        local += __shfl_down(local, off, 64);

    int lane = tid & 63, wid = tid >> 6;
    if (lane == 0) smem[wid] = local;
    __syncthreads();
    if (tid == 0) {
        float s = 0.0f;
        #pragma unroll
        for (int w = 0; w < BLOCK / 64; ++w) s += smem[w];
        partials[blockIdx.x] = s;
    }
}

// One block reduces the per-block partials and writes the final scaled loss.
__global__ __launch_bounds__(256)
void reduce_kernel(const float* __restrict__ partials,
                   float* __restrict__ out,
                   int n, float invB) {
    int tid = threadIdx.x;
    float local = 0.0f;
    for (int i = tid; i < n; i += 256) local += partials[i];

    #pragma unroll
    for (int off = 32; off > 0; off >>= 1)
        local += __shfl_down(local, off, 64);

    __shared__ float smem[4];
    int lane = tid & 63, wid = tid >> 6;
    if (lane == 0) smem[wid] = local;
    __syncthreads();
    if (tid == 0)
        out[0] = (smem[0] + smem[1] + smem[2] + smem[3]) * invB;
}

extern "C" void kernel_launch(void* const* d_in, const int* in_sizes, int n_in,
                              void* d_out, int out_size, void* d_ws, size_t ws_size,
                              hipStream_t stream) {
    const float* y_pre  = (const float*)d_in[0];
    const float* y_true = (const float*)d_in[1];
    float* out = (float*)d_out;
    float* partials = (float*)d_ws;

    int cells  = in_sizes[0] / 10;          // B * 7 * 7
    int B      = cells / 49;
    float invB = 1.0f / (float)B;

    int blocks = (cells + TILE - 1) / TILE;         // 6272 for B=65536

    yolo_loss_kernel<<<blocks, BLOCK, 0, stream>>>(y_pre, y_true, partials, cells);
    reduce_kernel<<<1, 256, 0, stream>>>(partials, out, blocks, invB);
}

// Round 4
// 226.856 us; speedup vs baseline: 1.0029x; 1.0029x over previous
//
#include <hip/hip_runtime.h>

constexpr float IMG_SIZE = 448.0f;
constexpr float GSZ = 64.0f;           // IMG_SIZE / GRID_NUM
constexpr float LAMBDA_COORD = 5.0f;
constexpr float LAMBDA_NOOBJ = 0.1f;
constexpr float EPSF = 1e-12f;

#define BLOCK 256
#define TILE 256                       // cells per tile (1 cell/thread)
#define PRE_F4 (TILE * 10 / 4)         // 640 float4 of y_pre per tile
#define TRU_F4 (TILE * 5 / 4)          // 320 float4 of y_true per tile
#define TILE_F4 (PRE_F4 + TRU_F4)      // 960 float4 = 15 KB per tile
#define GRID 1280                      // 5 blocks/CU * 256 CUs, %8 == 0

// Faithful port of reference _iou (including the y1_t = cy_t + w_t/2 typo).
__device__ __forceinline__ float iou_one(const float* __restrict__ b,
                                         float tx, float ty, float tw, float th,
                                         float gj, float gi) {
    float cx_p = b[0] * GSZ + gj * GSZ;
    float cy_p = b[1] * GSZ + gi * GSZ;
    float w_p  = b[2] * IMG_SIZE;
    float h_p  = b[3] * IMG_SIZE;
    float x0p = cx_p - 0.5f * w_p, x1p = cx_p + 0.5f * w_p;
    float y0p = cy_p - 0.5f * h_p, y1p = cy_p + 0.5f * h_p;

    float cx_t = tx * GSZ + gj * GSZ;
    float cy_t = ty * GSZ + gi * GSZ;
    float w_t  = tw * IMG_SIZE;
    float h_t  = th * IMG_SIZE;
    float x0t = cx_t - 0.5f * w_t, x1t = cx_t + 0.5f * w_t;
    float y0t = cy_t - 0.5f * h_t;
    float y1t = cy_t + 0.5f * w_t;   // faithful typo: w_t, not h_t

    float ux0 = fmaxf(x0p, x0t), ux1 = fminf(x1p, x1t);
    float uy0 = fmaxf(y0p, y0t), uy1 = fminf(y1p, y1t);
    bool valid = (ux0 < ux1) && (uy0 < uy1);
    float au = (ux1 - ux0) * (uy1 - uy0);
    float ap = (x1p - x0p) * (y1p - y0p);
    float at = (x1t - x0t) * (y1t - y0t);
    float res = au / (ap + at - au + EPSF);
    return valid ? res : 0.0f;
}

// Per-cell loss contribution (unscaled; reduce kernel applies 1/B).
__device__ __forceinline__ float cell_loss(const float* __restrict__ p,
                                           const float* __restrict__ t,
                                           float gj, float gi) {
    float iou0 = iou_one(p,     t[0], t[1], t[2], t[3], gj, gi);
    float iou1 = iou_one(p + 5, t[0], t[1], t[2], t[3], gj, gi);
    bool obj = (t[4] == 1.0f);
    bool ch0 = iou0 > iou1;
    float loss;
    if (obj) {
        float cp = ch0 ? p[4] : p[9];
        float ct = ch0 ? iou0 : iou1;
        float d  = cp - ct;
        loss = d * d;
        float dx = (ch0 ? p[0] : p[5]) - t[0];
        float dy = (ch0 ? p[1] : p[6]) - t[1];
        loss += LAMBDA_COORD * (dx * dx + dy * dy);
        float wp = fmaxf(ch0 ? p[2] : p[7], EPSF);
        float hp = fmaxf(ch0 ? p[3] : p[8], EPSF);
        float wt = fmaxf(t[2], EPSF);
        float ht = fmaxf(t[3], EPSF);
        float dw = sqrtf(wp) - sqrtf(wt);
        float dh = sqrtf(hp) - sqrtf(ht);
        loss += LAMBDA_COORD * (dw * dw + dh * dh);
    } else {
        loss = LAMBDA_NOOBJ * (p[4] * p[4] + p[9] * p[9]);
    }
    return loss;
}

// Chunk c of a tile: c in [0,640) -> y_pre float4, [640,960) -> y_true float4.
__device__ __forceinline__ float4 ld_chunk(const float4* __restrict__ pre4,
                                           const float4* __restrict__ tru4,
                                           int tile, int c) {
    if (c < PRE_F4) return pre4[(long long)tile * PRE_F4 + c];
    return tru4[(long long)tile * TRU_F4 + (c - PRE_F4)];
}

__global__ __launch_bounds__(BLOCK, 5)
void yolo_loss_kernel(const float* __restrict__ y_pre,
                      const float* __restrict__ y_true,
                      float* __restrict__ partials,
                      int cells) {
    // Double-buffered 15 KB tile: persistent blocks, 1 barrier per tile,
    // tile k+1's global loads in flight (in regs) during compute of tile k.
    __shared__ float4 sbuf[2][TILE_F4];    // 2 x 15 KB
    __shared__ float smem[BLOCK / 64];

    const float4* pre4 = (const float4*)y_pre;
    const float4* tru4 = (const float4*)y_true;

    int tid = threadIdx.x;
    int fullTiles = cells / TILE;
    float local = 0.0f;

    int tile = blockIdx.x;
    bool have = tile < fullTiles;
    float4 r0, r1, r2, r3;
    if (have) {                              // prologue: tile 0 -> regs
        r0 = ld_chunk(pre4, tru4, tile, tid);
        r1 = ld_chunk(pre4, tru4, tile, tid + 256);
        r2 = ld_chunk(pre4, tru4, tile, tid + 512);
        if (tid < TILE_F4 - 768) r3 = ld_chunk(pre4, tru4, tile, tid + 768);
    }
    int cur = 0;
    while (have) {
        // (1) regs(tile k) -> LDS buf[cur]  (compiler inserts vmcnt waits)
        float4* db = sbuf[cur];
        db[tid]       = r0;
        db[tid + 256] = r1;
        db[tid + 512] = r2;
        if (tid < TILE_F4 - 768) db[tid + 768] = r3;
        __syncthreads();                     // buf[cur] ready for everyone

        // (2) issue tile k+1 loads NOW; latency hides under compute(k)
        int next = tile + (int)gridDim.x;
        bool haveNext = next < fullTiles;
        if (haveNext) {
            r0 = ld_chunk(pre4, tru4, next, tid);
            r1 = ld_chunk(pre4, tru4, next, tid + 256);
            r2 = ld_chunk(pre4, tru4, next, tid + 512);
            if (tid < TILE_F4 - 768) r3 = ld_chunk(pre4, tru4, next, tid + 768);
        }

        // (3) compute tile k from LDS (thread t <-> cell t of the tile)
        const float* sp = (const float*)db;
        const float* p  = sp + tid * 10;
        const float* tr = sp + TILE * 10 + tid * 5;
        int rc = (tile * TILE + tid) % 49;
        int gi = rc / 7;
        int gj = rc - gi * 7;
        local += cell_loss(p, tr, (float)gj, (float)gi);

        // One barrier per tile is sound: writes to buf[cur] recur only at
        // iter k+2, gated by iter k+1's barrier which follows compute(k).
        cur ^= 1;
        tile = next;
        have = haveNext;
    }

    // Scalar tail (cells % 256 != 0) — block 0, direct global reads.
    if (blockIdx.x == 0) {
        int c = fullTiles * TILE + tid;
        if (c < cells) {
            int rc = c % 49;
            local += cell_loss(y_pre + (size_t)c * 10, y_true + (size_t)c * 5,
                               (float)(rc % 7), (float)(rc / 7));
        }
    }

    // Wave-64 shuffle reduce; one plain store per block.
    #pragma unroll
    for (int off = 32; off > 0; off >>= 1)
        local += __shfl_down(local, off, 64);

    int lane = tid & 63, wid = tid >> 6;
    if (lane == 0) smem[wid] = local;
    __syncthreads();
    if (tid == 0) {
        float s = 0.0f;
        #pragma unroll
        for (int w = 0; w < BLOCK / 64; ++w) s += smem[w];
        partials[blockIdx.x] = s;
    }
}

// One block reduces the per-block partials and writes the final scaled loss.
__global__ __launch_bounds__(256)
void reduce_kernel(const float* __restrict__ partials,
                   float* __restrict__ out,
                   int n, float invB) {
    int tid = threadIdx.x;
    float local = 0.0f;
    for (int i = tid; i < n; i += 256) local += partials[i];

    #pragma unroll
    for (int off = 32; off > 0; off >>= 1)
        local += __shfl_down(local, off, 64);

    __shared__ float smem[4];
    int lane = tid & 63, wid = tid >> 6;
    if (lane == 0) smem[wid] = local;
    __syncthreads();
    if (tid == 0)
        out[0] = (smem[0] + smem[1] + smem[2] + smem[3]) * invB;
}

extern "C" void kernel_launch(void* const* d_in, const int* in_sizes, int n_in,
                              void* d_out, int out_size, void* d_ws, size_t ws_size,
                              hipStream_t stream) {
    const float* y_pre  = (const float*)d_in[0];
    const float* y_true = (const float*)d_in[1];
    float* out = (float*)d_out;
    float* partials = (float*)d_ws;

    int cells  = in_sizes[0] / 10;          // B * 7 * 7
    int B      = cells / 49;
    float invB = 1.0f / (float)B;

    int blocks = GRID;
    if (blocks > (cells + TILE - 1) / TILE) blocks = (cells + TILE - 1) / TILE;
    if (blocks < 1) blocks = 1;

    yolo_loss_kernel<<<blocks, BLOCK, 0, stream>>>(y_pre, y_true, partials, cells);
    reduce_kernel<<<1, 256, 0, stream>>>(partials, out, blocks, invB);
}